// Round 1
// baseline (409.283 us; speedup 1.0000x reference)
//
#include <hip/hip_runtime.h>
#include <hip/hip_bf16.h>

typedef unsigned short u16;
typedef u16 us8 __attribute__((ext_vector_type(8)));
typedef __bf16 bf16x8 __attribute__((ext_vector_type(8)));
typedef float f32x4 __attribute__((ext_vector_type(4)));

#define NDIM 4096

__device__ __forceinline__ u16 bfbits(float f) {
    __hip_bfloat16 h = __float2bfloat16(f);
    return __builtin_bit_cast(u16, h);
}

__device__ __forceinline__ void gload_lds16(const u16* g, u16* l) {
    __builtin_amdgcn_global_load_lds((__attribute__((address_space(1))) void*)g,
                                     (__attribute__((address_space(3))) void*)l,
                                     16, 0, 0);
}

// ---------------------------------------------------------------------------
// Cb[u][k] = bf16(cos(pi * k * (u+0.5) / 4096)), row-major [4096][4096].
// Exact integer phase: angle = 2*pi * ((k*(2u+1)) mod 16384) / 16384.
// 8 elements per thread, one us8 (16B) store.
__global__ __launch_bounds__(256) void k_gencos(u16* __restrict__ Cb) {
    int idx = blockIdx.x * 256 + threadIdx.x;      // 2,097,152 threads total
    int u = idx >> 9;                              // 512 threads per row
    int k0 = (idx & 511) * 8;
    unsigned step = (unsigned)(2 * u + 1);
    us8 out;
#pragma unroll
    for (int i = 0; i < 8; ++i) {
        unsigned t = ((unsigned)(k0 + i) * step) & 16383u;
        out[i] = bfbits(cosf((float)t * 3.8349519697141029e-4f)); // 2pi/16384
    }
    *(us8*)&Cb[(size_t)idx * 8] = out;
}

// ---------------------------------------------------------------------------
// Xt[j][i] = bf16(X[i][j]); 32x32 LDS tile transpose, 256 threads.
__global__ __launch_bounds__(256) void k_transpose_bf16(const float* __restrict__ X,
                                                        u16* __restrict__ Xt) {
    __shared__ float tile[32][33];
    int b  = blockIdx.x;
    int bx = (b & 127) * 32;   // source col origin
    int by = (b >> 7) * 32;    // source row origin
    int tx = threadIdx.x & 31, ty = threadIdx.x >> 5;   // 32 x 8
#pragma unroll
    for (int r = 0; r < 32; r += 8)
        tile[ty + r][tx] = X[(size_t)(by + ty + r) * NDIM + bx + tx];
    __syncthreads();
#pragma unroll
    for (int r = 0; r < 32; r += 8)
        Xt[(size_t)(bx + ty + r) * NDIM + by + tx] = bfbits(tile[tx][ty + r]);
}

// ---------------------------------------------------------------------------
// D = A @ B^T, A/B bf16 row-major [4096][4096] (B stored as B[n][k]).
// m97 structure: 128x128 tile, BK=32, 4 waves (2x2), 4x4 16x16x32 frags/wave,
// global_load_lds width-16 staging, 2 barriers per K-step.
template <bool OUT_BF16>
__global__ __launch_bounds__(256) void gemm_bt(const u16* __restrict__ A,
                                               const u16* __restrict__ B,
                                               void* __restrict__ Cout) {
    __shared__ u16 As[128 * 32];
    __shared__ u16 Bs[128 * 32];

    const int tid  = threadIdx.x;
    const int wave = tid >> 6;
    const int lane = tid & 63;

    // XCD-aware bijective swizzle (gridDim.x = 1024, divisible by 8)
    int bid = blockIdx.x;
    int cpx = gridDim.x >> 3;
    int swz = (bid & 7) * cpx + (bid >> 3);
    const int nbn = NDIM / 128;
    const int bm  = (swz / nbn) * 128;
    const int bn  = (swz % nbn) * 128;

    const int wr = wave >> 1, wc = wave & 1;   // 2x2 wave grid, 64x64 each

    f32x4 acc[4][4] = {};

    // --- staging addressing: chunk c covers LDS bytes [c*1024, c*1024+1024)
    //     = tile rows [16c, 16c+16), lane l -> row 16c + l/4, k-off (l%4)*8
    const int c0   = wave * 2;
    const int rl   = lane >> 2;
    const int koff = (lane & 3) * 8;
    const u16* ga0 = A + (size_t)(bm + c0 * 16 + rl) * NDIM + koff;
    const u16* ga1 = ga0 + 16 * NDIM;
    const u16* gb0 = B + (size_t)(bn + c0 * 16 + rl) * NDIM + koff;
    const u16* gb1 = gb0 + 16 * NDIM;
    u16* la0 = &As[c0 * 512 + lane * 8];
    u16* la1 = la0 + 512;
    u16* lb0 = &Bs[c0 * 512 + lane * 8];
    u16* lb1 = lb0 + 512;

    // --- fragment read addressing (16x16x32: row = lane&15, k = (lane>>4)*8)
    const int fr = lane & 15;
    const int kg = (lane >> 4) * 8;
    const u16* fa = &As[(wr * 64 + fr) * 32 + kg];
    const u16* fb = &Bs[(wc * 64 + fr) * 32 + kg];

    for (int k0 = 0; k0 < NDIM; k0 += 32) {
        gload_lds16(ga0 + k0, la0);
        gload_lds16(ga1 + k0, la1);
        gload_lds16(gb0 + k0, lb0);
        gload_lds16(gb1 + k0, lb1);
        __syncthreads();   // compiler drains vmcnt before barrier

        bf16x8 a[4], b[4];
#pragma unroll
        for (int i = 0; i < 4; ++i)
            a[i] = __builtin_bit_cast(bf16x8, *(const us8*)(fa + i * 16 * 32));
#pragma unroll
        for (int j = 0; j < 4; ++j)
            b[j] = __builtin_bit_cast(bf16x8, *(const us8*)(fb + j * 16 * 32));
#pragma unroll
        for (int i = 0; i < 4; ++i)
#pragma unroll
            for (int j = 0; j < 4; ++j)
                acc[i][j] = __builtin_amdgcn_mfma_f32_16x16x32_bf16(a[i], b[j],
                                                                    acc[i][j], 0, 0, 0);
        __syncthreads();
    }

    // --- epilogue: C/D layout col = lane&15, row = (lane>>4)*4 + reg
    const int orow = bm + wr * 64 + (lane >> 4) * 4;
    const int ocol = bn + wc * 64 + (lane & 15);
#pragma unroll
    for (int i = 0; i < 4; ++i)
#pragma unroll
        for (int j = 0; j < 4; ++j) {
            f32x4 v = acc[i][j];
#pragma unroll
            for (int r = 0; r < 4; ++r) {
                size_t off = (size_t)(orow + i * 16 + r) * NDIM + (ocol + j * 16);
                if (OUT_BF16)
                    ((u16*)Cout)[off] = bfbits(v[r]);
                else
                    ((float*)Cout)[off] = v[r];
            }
        }
}

// ---------------------------------------------------------------------------
extern "C" void kernel_launch(void* const* d_in, const int* in_sizes, int n_in,
                              void* d_out, int out_size, void* d_ws, size_t ws_size,
                              hipStream_t stream) {
    const float* X = (const float*)d_in[0];
    float* Y = (float*)d_out;

    const size_t NN = (size_t)NDIM * NDIM;
    u16* Cb  = (u16*)d_ws;          // cos table, bf16
    u16* Xbt = Cb + NN;             // X^T, bf16
    u16* W   = Xbt + NN;            // intermediate C@X, bf16

    // 1. cos table: 4096^2 / (256*8) = 8192 blocks
    k_gencos<<<8192, 256, 0, stream>>>(Cb);
    // 2. transpose+convert X: 128*128 tiles
    k_transpose_bf16<<<16384, 256, 0, stream>>>(X, Xbt);
    // 3. W = Cb @ Xbt^T  (= C @ X), bf16 out
    gemm_bt<true><<<1024, 256, 0, stream>>>(Cb, Xbt, (void*)W);
    // 4. Y = W @ Cb^T    (= C @ X @ C^T), f32 out
    gemm_bt<false><<<1024, 256, 0, stream>>>(W, Cb, (void*)Y);
}

// Round 2
// 263.791 us; speedup vs baseline: 1.5515x; 1.5515x over previous
//
#include <hip/hip_runtime.h>
#include <hip/hip_bf16.h>

typedef unsigned short u16;
typedef u16 us8 __attribute__((ext_vector_type(8)));
typedef __bf16 bf16x8 __attribute__((ext_vector_type(8)));
typedef float f32x4 __attribute__((ext_vector_type(4)));

#define NDIM 4096
#define NT (NDIM / 64)   // 64 K-tiles of 64

__device__ __forceinline__ u16 bfbits(float f) {
    __hip_bfloat16 h = __float2bfloat16(f);
    return __builtin_bit_cast(u16, h);
}

__device__ __forceinline__ void gload_lds16(const u16* g, u16* l) {
    __builtin_amdgcn_global_load_lds((__attribute__((address_space(1))) void*)g,
                                     (__attribute__((address_space(3))) void*)l,
                                     16, 0, 0);
}

// ---------------------------------------------------------------------------
// Cb[u][k] = bf16(cos(pi * k * (u+0.5) / 4096)); exact integer phase mod 16384.
__global__ __launch_bounds__(256) void k_gencos(u16* __restrict__ Cb) {
    int idx = blockIdx.x * 256 + threadIdx.x;
    int u = idx >> 9;
    int k0 = (idx & 511) * 8;
    unsigned step = (unsigned)(2 * u + 1);
    us8 out;
#pragma unroll
    for (int i = 0; i < 8; ++i) {
        unsigned t = ((unsigned)(k0 + i) * step) & 16383u;
        out[i] = bfbits(cosf((float)t * 3.8349519697141029e-4f)); // 2pi/16384
    }
    *(us8*)&Cb[(size_t)idx * 8] = out;
}

// ---------------------------------------------------------------------------
// Xt[j][i] = bf16(X[i][j])
__global__ __launch_bounds__(256) void k_transpose_bf16(const float* __restrict__ X,
                                                        u16* __restrict__ Xt) {
    __shared__ float tile[32][33];
    int b  = blockIdx.x;
    int bx = (b & 127) * 32;
    int by = (b >> 7) * 32;
    int tx = threadIdx.x & 31, ty = threadIdx.x >> 5;
#pragma unroll
    for (int r = 0; r < 32; r += 8)
        tile[ty + r][tx] = X[(size_t)(by + ty + r) * NDIM + bx + tx];
    __syncthreads();
#pragma unroll
    for (int r = 0; r < 32; r += 8)
        Xt[(size_t)(bx + ty + r) * NDIM + by + tx] = bfbits(tile[tx][ty + r]);
}

// ---------------------------------------------------------------------------
// D = A @ B^T, 256x256 tile, BK=64, 8 waves, 8-phase schedule (T2+T3+T4+T5).
#define BAR() do { asm volatile("" ::: "memory"); __builtin_amdgcn_s_barrier(); \
                   asm volatile("" ::: "memory"); } while (0)

template <bool OUT_BF16>
__global__ __launch_bounds__(512, 2) void gemm256(const u16* __restrict__ A,
                                                  const u16* __restrict__ B,
                                                  void* __restrict__ Cout) {
    __shared__ u16 As[2 * 256 * 64];   // 64 KiB, dbuf x [256 rows][64 k] swizzled
    __shared__ u16 Bs[2 * 256 * 64];   // 64 KiB

    const int tid  = threadIdx.x;
    const int wave = tid >> 6;
    const int lane = tid & 63;

    const int bid = blockIdx.x;
    const int swz = (bid & 7) * ((int)gridDim.x >> 3) + (bid >> 3);  // 256%8==0 bijective
    const int bm  = (swz >> 4) * 256;
    const int bn  = (swz & 15) * 256;

    const int wr = wave >> 2;   // 0..1 -> 128 output rows
    const int wc = wave & 3;    // 0..3 -> 64 output cols

    // staging lane constants: lane covers row (chunk*8 + lane>>3), 16B slot (lane&7)
    // swizzle: LDS[row][slot] holds global col-slot (slot ^ (row&7))
    const int srow = lane >> 3;
    const int scol = ((lane & 7) ^ srow) << 3;   // global col element offset (pre-swizzled source)

    // reader constants: frag row = lane&15, k-slot = (lane>>4) + ks*4, XOR row&7
    const int fr   = lane & 15;
    const int hi   = lane >> 4;
    const int slot0 = ((hi)     ^ (lane & 7)) << 3;
    const int slot1 = ((hi + 4) ^ (lane & 7)) << 3;
    const int aRow = (wr * 128 + fr) * 64;
    const int bRow = (wc * 64 + fr) * 64;

    f32x4 acc[8][4] = {};
    bf16x8 aR[4][2], b01[2][2], b23[2][2];

#define STAGE(LARR, GP, ORG, H, TK, BOFF)                                       \
    do {                                                                        \
        const int _tk = (TK) & (NT - 1);                                        \
        _Pragma("unroll")                                                       \
        for (int q = 0; q < 2; ++q) {                                           \
            const u16* _g = (GP) + (size_t)((ORG) + (H) * 128 +                 \
                             (wave * 2 + q) * 8 + srow) * NDIM + _tk * 64 + scol; \
            gload_lds16(_g, LARR + (BOFF) + (H) * 8192 + (wave * 2 + q) * 512 + lane * 8); \
        }                                                                       \
    } while (0)

#define LOAD_A(MB, BOFF)                                                        \
    _Pragma("unroll")                                                           \
    for (int mm = 0; mm < 4; ++mm) {                                            \
        aR[mm][0] = __builtin_bit_cast(bf16x8, *(const us8*)(As + (BOFF) + aRow + ((MB) + mm) * 1024 + slot0)); \
        aR[mm][1] = __builtin_bit_cast(bf16x8, *(const us8*)(As + (BOFF) + aRow + ((MB) + mm) * 1024 + slot1)); \
    }

#define LOAD_B(DST, NB, BOFF)                                                   \
    _Pragma("unroll")                                                           \
    for (int nn = 0; nn < 2; ++nn) {                                            \
        DST[nn][0] = __builtin_bit_cast(bf16x8, *(const us8*)(Bs + (BOFF) + bRow + ((NB) + nn) * 1024 + slot0)); \
        DST[nn][1] = __builtin_bit_cast(bf16x8, *(const us8*)(Bs + (BOFF) + bRow + ((NB) + nn) * 1024 + slot1)); \
    }

#define MFMA_Q(MB, NB, BREG)                                                    \
    do {                                                                        \
        __builtin_amdgcn_s_setprio(1);                                          \
        _Pragma("unroll")                                                       \
        for (int mm = 0; mm < 4; ++mm)                                          \
            _Pragma("unroll")                                                   \
            for (int nn = 0; nn < 2; ++nn) {                                    \
                acc[(MB)+mm][(NB)+nn] = __builtin_amdgcn_mfma_f32_16x16x32_bf16(aR[mm][0], BREG[nn][0], acc[(MB)+mm][(NB)+nn], 0, 0, 0); \
                acc[(MB)+mm][(NB)+nn] = __builtin_amdgcn_mfma_f32_16x16x32_bf16(aR[mm][1], BREG[nn][1], acc[(MB)+mm][(NB)+nn], 0, 0, 0); \
            }                                                                   \
        __builtin_amdgcn_s_setprio(0);                                          \
    } while (0)

    // ---- prologue: B(0)h0,h1 A(0)h0,h1 -> buf0; B(1)h0,h1 -> buf1 (12 loads)
    STAGE(Bs, B, bn, 0, 0, 0);
    STAGE(Bs, B, bn, 1, 0, 0);
    STAGE(As, A, bm, 0, 0, 0);
    STAGE(As, A, bm, 1, 0, 0);
    STAGE(Bs, B, bn, 0, 1, 16384);
    STAGE(Bs, B, bn, 1, 1, 16384);
    asm volatile("s_waitcnt vmcnt(4)" ::: "memory");   // tile0 complete, B(1) in flight
    BAR();

    for (int t = 0; t < NT; t += 2) {
        // phase 1: tile t (buf0) q(m0-3,n0-1); stage A(t+1)h0 -> buf1
        LOAD_A(0, 0);
        LOAD_B(b01, 0, 0);
        STAGE(As, A, bm, 0, t + 1, 16384);
        BAR();
        MFMA_Q(0, 0, b01);
        BAR();
        // phase 2: q(m0-3,n2-3); stage A(t+1)h1 -> buf1
        LOAD_B(b23, 2, 0);
        STAGE(As, A, bm, 1, t + 1, 16384);
        BAR();
        MFMA_Q(0, 2, b23);
        BAR();
        // phase 3: q(m4-7,n2-3); stage B(t+2)h0 -> buf0 (B reads of t done ph2)
        LOAD_A(4, 0);
        STAGE(Bs, B, bn, 0, t + 2, 0);
        BAR();
        MFMA_Q(4, 2, b23);
        BAR();
        // phase 4: q(m4-7,n0-1); stage B(t+2)h1 -> buf0; counted wait for tile t+1
        STAGE(Bs, B, bn, 1, t + 2, 0);
        BAR();
        MFMA_Q(4, 0, b01);
        asm volatile("s_waitcnt vmcnt(4)" ::: "memory"); // completes A(t+1) stages
        BAR();
        // phase 5: tile t+1 (buf1) q(m0-3,n0-1); stage A(t+2)h0 -> buf0 (A reads of t done ph3)
        LOAD_A(0, 16384);
        LOAD_B(b01, 0, 16384);
        STAGE(As, A, bm, 0, t + 2, 0);
        BAR();
        MFMA_Q(0, 0, b01);
        BAR();
        // phase 6: q(m0-3,n2-3); stage A(t+2)h1 -> buf0
        LOAD_B(b23, 2, 16384);
        STAGE(As, A, bm, 1, t + 2, 0);
        BAR();
        MFMA_Q(0, 2, b23);
        BAR();
        // phase 7: q(m4-7,n2-3); stage B(t+3)h0 -> buf1 (B reads of t+1 done ph6)
        LOAD_A(4, 16384);
        STAGE(Bs, B, bn, 0, t + 3, 16384);
        BAR();
        MFMA_Q(4, 2, b23);
        BAR();
        // phase 8: q(m4-7,n0-1); stage B(t+3)h1 -> buf1; counted wait for tile t+2
        STAGE(Bs, B, bn, 1, t + 3, 16384);
        BAR();
        MFMA_Q(4, 0, b01);
        asm volatile("s_waitcnt vmcnt(4)" ::: "memory"); // completes A(t+2) stages
        BAR();
    }

    asm volatile("s_waitcnt vmcnt(0)" ::: "memory");  // drain wrapped tail stages

    // epilogue: C/D layout col = lane&15, row = (lane>>4)*4 + reg
    const int orow0 = bm + wr * 128 + hi * 4;
    const int ocol0 = bn + wc * 64 + fr;
#pragma unroll
    for (int m = 0; m < 8; ++m)
#pragma unroll
        for (int n = 0; n < 4; ++n) {
            f32x4 v = acc[m][n];
#pragma unroll
            for (int r = 0; r < 4; ++r) {
                size_t off = (size_t)(orow0 + m * 16 + r) * NDIM + (ocol0 + n * 16);
                if (OUT_BF16)
                    ((u16*)Cout)[off] = bfbits(v[r]);
                else
                    ((float*)Cout)[off] = v[r];
            }
        }
#undef STAGE
#undef LOAD_A
#undef LOAD_B
#undef MFMA_Q
}

// ---------------------------------------------------------------------------
extern "C" void kernel_launch(void* const* d_in, const int* in_sizes, int n_in,
                              void* d_out, int out_size, void* d_ws, size_t ws_size,
                              hipStream_t stream) {
    const float* X = (const float*)d_in[0];
    float* Y = (float*)d_out;

    const size_t NN = (size_t)NDIM * NDIM;
    u16* Cb  = (u16*)d_ws;
    u16* Xbt = Cb + NN;
    u16* W   = Xbt + NN;

    k_gencos<<<8192, 256, 0, stream>>>(Cb);
    k_transpose_bf16<<<16384, 256, 0, stream>>>(X, Xbt);
    // W = C @ X   (bf16 out)
    gemm256<true><<<256, 512, 0, stream>>>(Cb, Xbt, (void*)W);
    // Y = W @ C^T (f32 out)
    gemm256<false><<<256, 512, 0, stream>>>(W, Cb, (void*)Y);
}

// Round 3
// 178.426 us; speedup vs baseline: 2.2939x; 1.4784x over previous
//
#include <hip/hip_runtime.h>
#include <hip/hip_bf16.h>

typedef unsigned short u16;
typedef u16 us4 __attribute__((ext_vector_type(4)));
typedef u16 us8 __attribute__((ext_vector_type(8)));
typedef __bf16 bf16x8 __attribute__((ext_vector_type(8)));
typedef float f32x4 __attribute__((ext_vector_type(4)));

#define NDIM 4096
#define HDIM 2048

__device__ __forceinline__ u16 bfbits(float f) {
    __hip_bfloat16 h = __float2bfloat16(f);
    return __builtin_bit_cast(u16, h);
}
__device__ __forceinline__ float bf2f(u16 b) {
    return __builtin_bit_cast(float, ((unsigned)b) << 16);
}

__device__ __forceinline__ void gload_lds16(const u16* g, u16* l) {
    __builtin_amdgcn_global_load_lds((__attribute__((address_space(1))) void*)g,
                                     (__attribute__((address_space(3))) void*)l,
                                     16, 0, 0);
}

// ---------------------------------------------------------------------------
// Ce[u][k'] = cos(pi*(2k')  *(u+0.5)/4096)  = cos(2pi*(2k'  *(2u+1) mod 16384)/16384)
// Co[u][k'] = cos(pi*(2k'+1)*(u+0.5)/4096)  = cos(2pi*((2k'+1)*(2u+1) mod 16384)/16384)
// u,k' in [0,2048); exact integer phase.
__global__ __launch_bounds__(256) void k_gencos2(u16* __restrict__ Ce, u16* __restrict__ Co) {
    int idx = blockIdx.x * 256 + threadIdx.x;      // 524288 threads
    int u = idx >> 8;
    int k0 = (idx & 255) * 8;
    unsigned step = (unsigned)(2 * u + 1);
    us8 e, o;
#pragma unroll
    for (int i = 0; i < 8; ++i) {
        unsigned kk = (unsigned)(k0 + i);
        unsigned te = (2u * kk * step) & 16383u;
        unsigned to = ((2u * kk + 1u) * step) & 16383u;
        e[i] = bfbits(cosf((float)te * 3.8349519697141029e-4f)); // 2pi/16384
        o[i] = bfbits(cosf((float)to * 3.8349519697141029e-4f));
    }
    *(us8*)&Ce[(size_t)idx * 8] = e;
    *(us8*)&Co[(size_t)idx * 8] = o;
}

// ---------------------------------------------------------------------------
// Xe[j][k'] = bf16(X[2k'][j]), Xo[j][k'] = bf16(X[2k'+1][j]);  j<4096, k'<2048.
// 64x64 source tiles via LDS.
__global__ __launch_bounds__(256) void k_transpose_split(const float* __restrict__ X,
                                                         u16* __restrict__ Xe,
                                                         u16* __restrict__ Xo) {
    __shared__ float tile[64][65];
    int b  = blockIdx.x;
    int bx = (b & 63) * 64;    // source col origin (j)
    int by = (b >> 6) * 64;    // source row origin (k)
    int t  = threadIdx.x;
    int lr = t >> 4, lc = (t & 15) * 4;
#pragma unroll
    for (int r = 0; r < 64; r += 16) {
        float4 v = *(const float4*)&X[(size_t)(by + lr + r) * NDIM + bx + lc];
        tile[lr + r][lc + 0] = v.x;
        tile[lr + r][lc + 1] = v.y;
        tile[lr + r][lc + 2] = v.z;
        tile[lr + r][lc + 3] = v.w;
    }
    __syncthreads();
    int jl = t >> 2;           // 0..63 output row (j - bx)
    int s8 = (t & 3) * 8;      // k' sub-offset 0,8,16,24
    us8 e, o;
#pragma unroll
    for (int i = 0; i < 8; ++i) {
        e[i] = bfbits(tile[2 * (s8 + i)][jl]);
        o[i] = bfbits(tile[2 * (s8 + i) + 1][jl]);
    }
    size_t base = (size_t)(bx + jl) * HDIM + (by >> 1) + s8;
    *(us8*)&Xe[base] = e;
    *(us8*)&Xo[base] = o;
}

// ---------------------------------------------------------------------------
// Butterfly 1: W[u] = S[u]+D[u], W[4095-u] = S[u]-D[u] (u<2048), written
// column-deinterleaved: We[i][q'] = W[i][2q'], Wo[i][q'] = W[i][2q'+1].
__global__ __launch_bounds__(256) void k_bfly1(const u16* __restrict__ S,
                                               const u16* __restrict__ D,
                                               u16* __restrict__ We,
                                               u16* __restrict__ Wo) {
    int idx = blockIdx.x * 256 + threadIdx.x;     // 2048*4096/8 threads
    int u  = idx >> 9;
    int j0 = (idx & 511) * 8;
    us8 s8 = *(const us8*)&S[(size_t)u * NDIM + j0];
    us8 d8 = *(const us8*)&D[(size_t)u * NDIM + j0];
    us4 et, ot, eb, ob;
#pragma unroll
    for (int i = 0; i < 4; ++i) {
        float se = bf2f(s8[2 * i]),     de = bf2f(d8[2 * i]);
        float so = bf2f(s8[2 * i + 1]), dd = bf2f(d8[2 * i + 1]);
        et[i] = bfbits(se + de);  eb[i] = bfbits(se - de);
        ot[i] = bfbits(so + dd);  ob[i] = bfbits(so - dd);
    }
    size_t ct = (size_t)u * HDIM + (j0 >> 1);
    size_t cb = (size_t)(NDIM - 1 - u) * HDIM + (j0 >> 1);
    *(us4*)&We[ct] = et;  *(us4*)&Wo[ct] = ot;
    *(us4*)&We[cb] = eb;  *(us4*)&Wo[cb] = ob;
}

// ---------------------------------------------------------------------------
// Butterfly 2: Y[i][v'] = S2+D2, Y[i][4095-v'] = S2-D2 (v'<2048), f32 out.
__global__ __launch_bounds__(256) void k_bfly2(const u16* __restrict__ S2,
                                               const u16* __restrict__ D2,
                                               float* __restrict__ Y) {
    int idx = blockIdx.x * 256 + threadIdx.x;     // 4096*2048/8 threads
    int i  = idx >> 8;
    int v0 = (idx & 255) * 8;
    us8 s8 = *(const us8*)&S2[(size_t)i * HDIM + v0];
    us8 d8 = *(const us8*)&D2[(size_t)i * HDIM + v0];
    float sum[8], dif[8];
#pragma unroll
    for (int t = 0; t < 8; ++t) {
        float s = bf2f(s8[t]), d = bf2f(d8[t]);
        sum[t] = s + d;  dif[t] = s - d;
    }
    f32x4 a0, a1, r0, r1;
#pragma unroll
    for (int w = 0; w < 4; ++w) {
        a0[w] = sum[w];  a1[w] = sum[w + 4];
        r0[w] = dif[7 - w];  r1[w] = dif[3 - w];
    }
    float* row = Y + (size_t)i * NDIM;
    *(f32x4*)&row[v0]           = a0;
    *(f32x4*)&row[v0 + 4]       = a1;
    *(f32x4*)&row[4088 - v0]    = r0;   // cols 4088-v0 .. 4091-v0 = mirror of v0+7..v0+4
    *(f32x4*)&row[4092 - v0]    = r1;   // cols 4092-v0 .. 4095-v0 = mirror of v0+3..v0
}

// ---------------------------------------------------------------------------
// D = A @ B^T, 256x256 tile, BK=64, 8 waves, 8-phase schedule (T2+T3+T4+T5).
// Grid = 256 blocks: blocks with half==0 compute A0@B0^T, half==1 A1@B1^T,
// outputs stacked at out and out + M*N. K = NTK*64. bf16 output.
#define BAR() do { asm volatile("" ::: "memory"); __builtin_amdgcn_s_barrier(); \
                   asm volatile("" ::: "memory"); } while (0)

template <int NTK, int LOG_NTN>
__global__ __launch_bounds__(512, 2) void gemm256h(const u16* __restrict__ A0,
                                                   const u16* __restrict__ A1,
                                                   const u16* __restrict__ B0,
                                                   const u16* __restrict__ B1,
                                                   u16* __restrict__ out) {
    constexpr int KD  = NTK * 64;
    constexpr int NTN = 1 << LOG_NTN;
    constexpr int LDC = NTN * 256;
    constexpr int MTILES = 128 >> LOG_NTN;

    __shared__ u16 As[2 * 256 * 64];
    __shared__ u16 Bs[2 * 256 * 64];

    const int tid  = threadIdx.x;
    const int wave = tid >> 6;
    const int lane = tid & 63;

    const int bid = blockIdx.x;
    const int swz = (bid & 7) * 32 + (bid >> 3);   // grid 256, bijective
    const int half = swz >> 7;
    const int r    = swz & 127;
    const int bm   = (r >> LOG_NTN) * 256;
    const int bn   = (r & (NTN - 1)) * 256;

    const u16* A = half ? A1 : A0;
    const u16* B = half ? B1 : B0;
    u16* Cp = out + (size_t)half * MTILES * 256 * LDC;

    const int wr = wave >> 2;   // 0..1 -> 128 output rows
    const int wc = wave & 3;    // 0..3 -> 64 output cols

    const int srow = lane >> 3;
    const int scol = ((lane & 7) ^ srow) << 3;   // pre-swizzled global col offset

    const int fr   = lane & 15;
    const int hi   = lane >> 4;
    const int slot0 = ((hi)     ^ (lane & 7)) << 3;
    const int slot1 = ((hi + 4) ^ (lane & 7)) << 3;
    const int aRow = (wr * 128 + fr) * 64;
    const int bRow = (wc * 64 + fr) * 64;

    f32x4 acc[8][4] = {};
    bf16x8 aR[4][2], b01[2][2], b23[2][2];

#define STAGE(LARR, GP, ORG, H, TK, BOFF)                                       \
    do {                                                                        \
        const int _tk = (TK) & (NTK - 1);                                       \
        _Pragma("unroll")                                                       \
        for (int q = 0; q < 2; ++q) {                                           \
            const u16* _g = (GP) + (size_t)((ORG) + (H) * 128 +                 \
                             (wave * 2 + q) * 8 + srow) * KD + _tk * 64 + scol; \
            gload_lds16(_g, LARR + (BOFF) + (H) * 8192 + (wave * 2 + q) * 512 + lane * 8); \
        }                                                                       \
    } while (0)

#define LOAD_A(MB, BOFF)                                                        \
    _Pragma("unroll")                                                           \
    for (int mm = 0; mm < 4; ++mm) {                                            \
        aR[mm][0] = __builtin_bit_cast(bf16x8, *(const us8*)(As + (BOFF) + aRow + ((MB) + mm) * 1024 + slot0)); \
        aR[mm][1] = __builtin_bit_cast(bf16x8, *(const us8*)(As + (BOFF) + aRow + ((MB) + mm) * 1024 + slot1)); \
    }

#define LOAD_B(DST, NB, BOFF)                                                   \
    _Pragma("unroll")                                                           \
    for (int nn = 0; nn < 2; ++nn) {                                            \
        DST[nn][0] = __builtin_bit_cast(bf16x8, *(const us8*)(Bs + (BOFF) + bRow + ((NB) + nn) * 1024 + slot0)); \
        DST[nn][1] = __builtin_bit_cast(bf16x8, *(const us8*)(Bs + (BOFF) + bRow + ((NB) + nn) * 1024 + slot1)); \
    }

#define MFMA_Q(MB, NB, BREG)                                                    \
    do {                                                                        \
        __builtin_amdgcn_s_setprio(1);                                          \
        _Pragma("unroll")                                                       \
        for (int mm = 0; mm < 4; ++mm)                                          \
            _Pragma("unroll")                                                   \
            for (int nn = 0; nn < 2; ++nn) {                                    \
                acc[(MB)+mm][(NB)+nn] = __builtin_amdgcn_mfma_f32_16x16x32_bf16(aR[mm][0], BREG[nn][0], acc[(MB)+mm][(NB)+nn], 0, 0, 0); \
                acc[(MB)+mm][(NB)+nn] = __builtin_amdgcn_mfma_f32_16x16x32_bf16(aR[mm][1], BREG[nn][1], acc[(MB)+mm][(NB)+nn], 0, 0, 0); \
            }                                                                   \
        __builtin_amdgcn_s_setprio(0);                                          \
    } while (0)

    // ---- prologue
    STAGE(Bs, B, bn, 0, 0, 0);
    STAGE(Bs, B, bn, 1, 0, 0);
    STAGE(As, A, bm, 0, 0, 0);
    STAGE(As, A, bm, 1, 0, 0);
    STAGE(Bs, B, bn, 0, 1, 16384);
    STAGE(Bs, B, bn, 1, 1, 16384);
    asm volatile("s_waitcnt vmcnt(4)" ::: "memory");   // tile0 complete
    BAR();

    for (int t = 0; t < NTK; t += 2) {
        LOAD_A(0, 0);
        LOAD_B(b01, 0, 0);
        STAGE(As, A, bm, 0, t + 1, 16384);
        BAR();
        MFMA_Q(0, 0, b01);
        BAR();
        LOAD_B(b23, 2, 0);
        STAGE(As, A, bm, 1, t + 1, 16384);
        BAR();
        MFMA_Q(0, 2, b23);
        BAR();
        LOAD_A(4, 0);
        STAGE(Bs, B, bn, 0, t + 2, 0);
        BAR();
        MFMA_Q(4, 2, b23);
        BAR();
        STAGE(Bs, B, bn, 1, t + 2, 0);
        BAR();
        MFMA_Q(4, 0, b01);
        asm volatile("s_waitcnt vmcnt(4)" ::: "memory");
        BAR();
        LOAD_A(0, 16384);
        LOAD_B(b01, 0, 16384);
        STAGE(As, A, bm, 0, t + 2, 0);
        BAR();
        MFMA_Q(0, 0, b01);
        BAR();
        LOAD_B(b23, 2, 16384);
        STAGE(As, A, bm, 1, t + 2, 0);
        BAR();
        MFMA_Q(0, 2, b23);
        BAR();
        LOAD_A(4, 16384);
        STAGE(Bs, B, bn, 0, t + 3, 16384);
        BAR();
        MFMA_Q(4, 2, b23);
        BAR();
        STAGE(Bs, B, bn, 1, t + 3, 16384);
        BAR();
        MFMA_Q(4, 0, b01);
        asm volatile("s_waitcnt vmcnt(4)" ::: "memory");
        BAR();
    }

    asm volatile("s_waitcnt vmcnt(0)" ::: "memory");

    const int orow0 = wr * 128 + hi * 4;
    const int ocol0 = bn + wc * 64 + fr;
#pragma unroll
    for (int m = 0; m < 8; ++m)
#pragma unroll
        for (int n = 0; n < 4; ++n) {
            f32x4 v = acc[m][n];
#pragma unroll
            for (int rr = 0; rr < 4; ++rr) {
                size_t off = (size_t)(bm + orow0 + m * 16 + rr) * LDC + (ocol0 + n * 16);
                Cp[off] = bfbits(v[rr]);
            }
        }
#undef STAGE
#undef LOAD_A
#undef LOAD_B
#undef MFMA_Q
}

// ---------------------------------------------------------------------------
extern "C" void kernel_launch(void* const* d_in, const int* in_sizes, int n_in,
                              void* d_out, int out_size, void* d_ws, size_t ws_size,
                              hipStream_t stream) {
    const float* X = (const float*)d_in[0];
    float* Y = (float*)d_out;

    const size_t QM = (size_t)HDIM * HDIM;   // 4M elems
    u16* Ce = (u16*)d_ws;                    // [2048][2048] bf16
    u16* Co = Ce + QM;                       // [2048][2048]
    u16* Xe = Co + QM;                       // [4096][2048]
    u16* Xo = Xe + 2 * QM;                   // [4096][2048]
    u16* S  = Xo + 2 * QM;                   // [2048][4096] (GEMM1 out, S then D)
    u16* D  = S + 2 * QM;                    // [2048][4096]
    // aliases (dead buffers reused):
    u16* We = Xe;                            // [4096][2048]  (over Xe)
    u16* Wo = Xo;                            // [4096][2048]  (over Xo)
    u16* S2 = S;                             // [4096][2048]  (over S)
    u16* D2 = D;                             // [4096][2048]  (over D)

    k_gencos2<<<2048, 256, 0, stream>>>(Ce, Co);
    k_transpose_split<<<4096, 256, 0, stream>>>(X, Xe, Xo);
    // GEMM1: S = Ce @ Xe^T, D = Co @ Xo^T   (M=2048, N=4096, K=2048)
    gemm256h<32, 4><<<256, 512, 0, stream>>>(Ce, Co, Xe, Xo, S);
    k_bfly1<<<4096, 256, 0, stream>>>(S, D, We, Wo);
    // GEMM2: S2 = We @ Ce^T, D2 = Wo @ Co^T (M=4096, N=2048, K=2048)
    gemm256h<32, 3><<<256, 512, 0, stream>>>(We, Wo, Ce, Co, S2);
    k_bfly2<<<4096, 256, 0, stream>>>(S2, D2, Y);
}

// Round 4
// 174.314 us; speedup vs baseline: 2.3480x; 1.0236x over previous
//
#include <hip/hip_runtime.h>
#include <hip/hip_bf16.h>

typedef unsigned short u16;
typedef u16 us4 __attribute__((ext_vector_type(4)));
typedef u16 us8 __attribute__((ext_vector_type(8)));
typedef __bf16 bf16x8 __attribute__((ext_vector_type(8)));
typedef float f32x4 __attribute__((ext_vector_type(4)));

#define NDIM 4096
#define HDIM 2048

__device__ __forceinline__ u16 bfbits(float f) {
    __hip_bfloat16 h = __float2bfloat16(f);
    return __builtin_bit_cast(u16, h);
}
__device__ __forceinline__ float bf2f(u16 b) {
    return __builtin_bit_cast(float, ((unsigned)b) << 16);
}

__device__ __forceinline__ void gload_lds16(const u16* g, u16* l) {
    __builtin_amdgcn_global_load_lds((__attribute__((address_space(1))) void*)g,
                                     (__attribute__((address_space(3))) void*)l,
                                     16, 0, 0);
}

// ---------------------------------------------------------------------------
// Ce[u][k'] = cos(pi*k'*(u+0.5)/2048), Co[u][k'] = cos(pi*(2k'+1)*(u+0.5)/4096)
__global__ __launch_bounds__(256) void k_gencos2(u16* __restrict__ Ce, u16* __restrict__ Co) {
    int idx = blockIdx.x * 256 + threadIdx.x;
    int u = idx >> 8;
    int k0 = (idx & 255) * 8;
    unsigned step = (unsigned)(2 * u + 1);
    us8 e, o;
#pragma unroll
    for (int i = 0; i < 8; ++i) {
        unsigned kk = (unsigned)(k0 + i);
        unsigned te = (2u * kk * step) & 16383u;
        unsigned to = ((2u * kk + 1u) * step) & 16383u;
        e[i] = bfbits(cosf((float)te * 3.8349519697141029e-4f)); // 2pi/16384
        o[i] = bfbits(cosf((float)to * 3.8349519697141029e-4f));
    }
    *(us8*)&Ce[(size_t)idx * 8] = e;
    *(us8*)&Co[(size_t)idx * 8] = o;
}

// ---------------------------------------------------------------------------
// Xe[j][k'] = bf16(X[2k'][j]), Xo[j][k'] = bf16(X[2k'+1][j])
__global__ __launch_bounds__(256) void k_transpose_split(const float* __restrict__ X,
                                                         u16* __restrict__ Xe,
                                                         u16* __restrict__ Xo) {
    __shared__ float tile[64][65];
    int b  = blockIdx.x;
    int bx = (b & 63) * 64;
    int by = (b >> 6) * 64;
    int t  = threadIdx.x;
    int lr = t >> 4, lc = (t & 15) * 4;
#pragma unroll
    for (int r = 0; r < 64; r += 16) {
        float4 v = *(const float4*)&X[(size_t)(by + lr + r) * NDIM + bx + lc];
        tile[lr + r][lc + 0] = v.x;
        tile[lr + r][lc + 1] = v.y;
        tile[lr + r][lc + 2] = v.z;
        tile[lr + r][lc + 3] = v.w;
    }
    __syncthreads();
    int jl = t >> 2;
    int s8 = (t & 3) * 8;
    us8 e, o;
#pragma unroll
    for (int i = 0; i < 8; ++i) {
        e[i] = bfbits(tile[2 * (s8 + i)][jl]);
        o[i] = bfbits(tile[2 * (s8 + i) + 1][jl]);
    }
    size_t base = (size_t)(bx + jl) * HDIM + (by >> 1) + s8;
    *(us8*)&Xe[base] = e;
    *(us8*)&Xo[base] = o;
}

// ---------------------------------------------------------------------------
// Butterfly 1: W[u] = S[u]+D[u], W[4095-u] = S[u]-D[u], column-deinterleaved.
__global__ __launch_bounds__(256) void k_bfly1(const u16* __restrict__ S,
                                               const u16* __restrict__ D,
                                               u16* __restrict__ We,
                                               u16* __restrict__ Wo) {
    int idx = blockIdx.x * 256 + threadIdx.x;
    int u  = idx >> 9;
    int j0 = (idx & 511) * 8;
    us8 s8 = *(const us8*)&S[(size_t)u * NDIM + j0];
    us8 d8 = *(const us8*)&D[(size_t)u * NDIM + j0];
    us4 et, ot, eb, ob;
#pragma unroll
    for (int i = 0; i < 4; ++i) {
        float se = bf2f(s8[2 * i]),     de = bf2f(d8[2 * i]);
        float so = bf2f(s8[2 * i + 1]), dd = bf2f(d8[2 * i + 1]);
        et[i] = bfbits(se + de);  eb[i] = bfbits(se - de);
        ot[i] = bfbits(so + dd);  ob[i] = bfbits(so - dd);
    }
    size_t ct = (size_t)u * HDIM + (j0 >> 1);
    size_t cb = (size_t)(NDIM - 1 - u) * HDIM + (j0 >> 1);
    *(us4*)&We[ct] = et;  *(us4*)&Wo[ct] = ot;
    *(us4*)&We[cb] = eb;  *(us4*)&Wo[cb] = ob;
}

// ---------------------------------------------------------------------------
// Butterfly 2: Y[i][v'] = S2+D2, Y[i][4095-v'] = S2-D2, f32 out.
__global__ __launch_bounds__(256) void k_bfly2(const u16* __restrict__ S2,
                                               const u16* __restrict__ D2,
                                               float* __restrict__ Y) {
    int idx = blockIdx.x * 256 + threadIdx.x;
    int i  = idx >> 8;
    int v0 = (idx & 255) * 8;
    us8 s8 = *(const us8*)&S2[(size_t)i * HDIM + v0];
    us8 d8 = *(const us8*)&D2[(size_t)i * HDIM + v0];
    float sum[8], dif[8];
#pragma unroll
    for (int t = 0; t < 8; ++t) {
        float s = bf2f(s8[t]), d = bf2f(d8[t]);
        sum[t] = s + d;  dif[t] = s - d;
    }
    f32x4 a0, a1, r0, r1;
#pragma unroll
    for (int w = 0; w < 4; ++w) {
        a0[w] = sum[w];  a1[w] = sum[w + 4];
        r0[w] = dif[7 - w];  r1[w] = dif[3 - w];
    }
    float* row = Y + (size_t)i * NDIM;
    *(f32x4*)&row[v0]        = a0;
    *(f32x4*)&row[v0 + 4]    = a1;
    *(f32x4*)&row[4088 - v0] = r0;
    *(f32x4*)&row[4092 - v0] = r1;
}

// ---------------------------------------------------------------------------
// D = A @ B^T, 256x256 tile, BK=64, 8 waves, 8-phase schedule, 3-half-deep
// counted-vmcnt pipeline (T2+T3+T4+T5).
// Halves are m-block/n-block unions so each phase's reads cover whole halves:
//   A-h0' = rows [0,64)+[128,192)  (read at ph1),  A-h1' = complement (ph3)
//   B-h0' = rows wc*64+[0,32) all wc (ph1),        B-h1' = complement (ph2)
#define BAR() do { asm volatile("" ::: "memory"); __builtin_amdgcn_s_barrier(); \
                   asm volatile("" ::: "memory"); } while (0)
#define WAITV(N) asm volatile("s_waitcnt vmcnt(" #N ")" ::: "memory")

template <int NTK, int LOG_NTN>
__global__ __launch_bounds__(512, 2) void gemm256h(const u16* __restrict__ A0,
                                                   const u16* __restrict__ A1,
                                                   const u16* __restrict__ B0,
                                                   const u16* __restrict__ B1,
                                                   u16* __restrict__ out) {
    constexpr int KD  = NTK * 64;
    constexpr int NTN = 1 << LOG_NTN;
    constexpr int LDC = NTN * 256;
    constexpr int MTILES = 128 >> LOG_NTN;

    __shared__ u16 As[2 * 256 * 64];
    __shared__ u16 Bs[2 * 256 * 64];

    const int tid  = threadIdx.x;
    const int wave = tid >> 6;
    const int lane = tid & 63;

    const int bid = blockIdx.x;
    const int swz = (bid & 7) * 32 + (bid >> 3);   // grid 256, bijective
    const int half = swz >> 7;
    const int r    = swz & 127;
    const int bm   = (r >> LOG_NTN) * 256;
    const int bn   = (r & (NTN - 1)) * 256;

    const u16* A = half ? A1 : A0;
    const u16* B = half ? B1 : B0;
    u16* Cp = out + (size_t)half * MTILES * 256 * LDC;

    const int wr = wave >> 2;
    const int wc = wave & 3;

    const int srow = lane >> 3;
    const int scol = ((lane & 7) ^ srow) << 3;     // pre-swizzled global col offset

    const int fr   = lane & 15;
    const int hi   = lane >> 4;
    const int slot0 = ((hi)     ^ (lane & 7)) << 3;
    const int slot1 = ((hi + 4) ^ (lane & 7)) << 3;
    const int aRow = (wr * 128 + fr) * 64;
    const int bRow = (wc * 64 + fr) * 64;

    // staging row origins (per wave, q in {0,1}): seg = wave*2+q
    //   A half H: row0 = H*64 + (seg&7)*8 + (seg>>3)*128
    //   B half H: row0 = H*32 + (seg&3)*8 + (seg>>2)*64

    f32x4 acc[8][4] = {};
    bf16x8 aR[4][2], b01[2][2], b23[2][2];

#define STAGE_A(TK, H, BOFF)                                                     \
    do {                                                                         \
        const int _tk = (TK) & (NTK - 1);                                        \
        _Pragma("unroll")                                                        \
        for (int q = 0; q < 2; ++q) {                                            \
            const int seg  = wave * 2 + q;                                       \
            const int row0 = (H) * 64 + (seg & 7) * 8 + (seg >> 3) * 128;        \
            const u16* _g = A + (size_t)(bm + row0 + srow) * KD + _tk * 64 + scol; \
            gload_lds16(_g, As + (BOFF) + row0 * 64 + lane * 8);                 \
        }                                                                        \
    } while (0)

#define STAGE_B(TK, H, BOFF)                                                     \
    do {                                                                         \
        const int _tk = (TK) & (NTK - 1);                                        \
        _Pragma("unroll")                                                        \
        for (int q = 0; q < 2; ++q) {                                            \
            const int seg  = wave * 2 + q;                                       \
            const int row0 = (H) * 32 + (seg & 3) * 8 + (seg >> 2) * 64;         \
            const u16* _g = B + (size_t)(bn + row0 + srow) * KD + _tk * 64 + scol; \
            gload_lds16(_g, Bs + (BOFF) + row0 * 64 + lane * 8);                 \
        }                                                                        \
    } while (0)

#define LOAD_A(MB, BOFF)                                                        \
    _Pragma("unroll")                                                           \
    for (int mm = 0; mm < 4; ++mm) {                                            \
        aR[mm][0] = __builtin_bit_cast(bf16x8, *(const us8*)(As + (BOFF) + aRow + ((MB) + mm) * 1024 + slot0)); \
        aR[mm][1] = __builtin_bit_cast(bf16x8, *(const us8*)(As + (BOFF) + aRow + ((MB) + mm) * 1024 + slot1)); \
    }

#define LOAD_B(DST, NB, BOFF)                                                   \
    _Pragma("unroll")                                                           \
    for (int nn = 0; nn < 2; ++nn) {                                            \
        DST[nn][0] = __builtin_bit_cast(bf16x8, *(const us8*)(Bs + (BOFF) + bRow + ((NB) + nn) * 1024 + slot0)); \
        DST[nn][1] = __builtin_bit_cast(bf16x8, *(const us8*)(Bs + (BOFF) + bRow + ((NB) + nn) * 1024 + slot1)); \
    }

#define MFMA_Q(MB, NB, BREG)                                                    \
    do {                                                                        \
        __builtin_amdgcn_s_setprio(1);                                          \
        _Pragma("unroll")                                                       \
        for (int mm = 0; mm < 4; ++mm)                                          \
            _Pragma("unroll")                                                   \
            for (int nn = 0; nn < 2; ++nn) {                                    \
                acc[(MB)+mm][(NB)+nn] = __builtin_amdgcn_mfma_f32_16x16x32_bf16(aR[mm][0], BREG[nn][0], acc[(MB)+mm][(NB)+nn], 0, 0, 0); \
                acc[(MB)+mm][(NB)+nn] = __builtin_amdgcn_mfma_f32_16x16x32_bf16(aR[mm][1], BREG[nn][1], acc[(MB)+mm][(NB)+nn], 0, 0, 0); \
            }                                                                   \
        __builtin_amdgcn_s_setprio(0);                                          \
    } while (0)

    // ---- prologue: 7 halves, steady-state mimic; vmcnt(6) completes tile 0
    STAGE_B(0, 0, 0);
    STAGE_A(0, 0, 0);
    STAGE_B(0, 1, 0);
    STAGE_A(0, 1, 0);
    STAGE_B(1, 0, 16384);
    STAGE_A(1, 0, 16384);
    STAGE_B(1, 1, 16384);
    WAITV(6);
    BAR();

    for (int t = 0; t < NTK; t += 2) {
        // ph1: compute t(buf0) q(m0-3,n0-1); stage A(t+1)h1' -> buf1
        LOAD_A(0, 0);
        LOAD_B(b01, 0, 0);
        STAGE_A(t + 1, 1, 16384);
        BAR();
        MFMA_Q(0, 0, b01);
        BAR();
        // ph2: q(m0-3,n2-3); stage B(t+2)h0' -> buf0
        LOAD_B(b23, 2, 0);
        STAGE_B(t + 2, 0, 0);
        BAR();
        MFMA_Q(0, 2, b23);
        BAR();
        // ph3: q(m4-7,n2-3); stage A(t+2)h0' -> buf0
        LOAD_A(4, 0);
        STAGE_A(t + 2, 0, 0);
        BAR();
        MFMA_Q(4, 2, b23);
        BAR();
        // ph4: q(m4-7,n0-1); stage B(t+2)h1' -> buf0; vmcnt(6) completes tile t+1
        STAGE_B(t + 2, 1, 0);
        BAR();
        MFMA_Q(4, 0, b01);
        WAITV(6);
        BAR();
        // ph5: compute t+1(buf1) q(m0-3,n0-1); stage A(t+2)h1' -> buf0
        LOAD_A(0, 16384);
        LOAD_B(b01, 0, 16384);
        STAGE_A(t + 2, 1, 0);
        BAR();
        MFMA_Q(0, 0, b01);
        BAR();
        // ph6: q(m0-3,n2-3); stage B(t+3)h0' -> buf1
        LOAD_B(b23, 2, 16384);
        STAGE_B(t + 3, 0, 16384);
        BAR();
        MFMA_Q(0, 2, b23);
        BAR();
        // ph7: q(m4-7,n2-3); stage A(t+3)h0' -> buf1
        LOAD_A(4, 16384);
        STAGE_A(t + 3, 0, 16384);
        BAR();
        MFMA_Q(4, 2, b23);
        BAR();
        // ph8: q(m4-7,n0-1); stage B(t+3)h1' -> buf1; vmcnt(6) completes tile t+2
        STAGE_B(t + 3, 1, 16384);
        BAR();
        MFMA_Q(4, 0, b01);
        WAITV(6);
        BAR();
    }

    asm volatile("s_waitcnt vmcnt(0)" ::: "memory");

    const int orow0 = wr * 128 + hi * 4;
    const int ocol0 = bn + wc * 64 + fr;
#pragma unroll
    for (int m = 0; m < 8; ++m)
#pragma unroll
        for (int n = 0; n < 4; ++n) {
            f32x4 v = acc[m][n];
#pragma unroll
            for (int rr = 0; rr < 4; ++rr) {
                size_t off = (size_t)(bm + orow0 + m * 16 + rr) * LDC + (ocol0 + n * 16);
                Cp[off] = bfbits(v[rr]);
            }
        }
#undef STAGE_A
#undef STAGE_B
#undef LOAD_A
#undef LOAD_B
#undef MFMA_Q
}

// ---------------------------------------------------------------------------
extern "C" void kernel_launch(void* const* d_in, const int* in_sizes, int n_in,
                              void* d_out, int out_size, void* d_ws, size_t ws_size,
                              hipStream_t stream) {
    const float* X = (const float*)d_in[0];
    float* Y = (float*)d_out;

    const size_t QM = (size_t)HDIM * HDIM;
    u16* Ce = (u16*)d_ws;
    u16* Co = Ce + QM;
    u16* Xe = Co + QM;
    u16* Xo = Xe + 2 * QM;
    u16* S  = Xo + 2 * QM;
    u16* D  = S + 2 * QM;
    u16* We = Xe;
    u16* Wo = Xo;
    u16* S2 = S;
    u16* D2 = D;

    k_gencos2<<<2048, 256, 0, stream>>>(Ce, Co);
    k_transpose_split<<<4096, 256, 0, stream>>>(X, Xe, Xo);
    gemm256h<32, 4><<<256, 512, 0, stream>>>(Ce, Co, Xe, Xo, S);
    k_bfly1<<<4096, 256, 0, stream>>>(S, D, We, Wo);
    gemm256h<32, 3><<<256, 512, 0, stream>>>(We, Wo, Ce, Co, S2);
    k_bfly2<<<4096, 256, 0, stream>>>(S2, D2, Y);
}